// Round 11
// baseline (56.415 us; speedup 1.0000x reference)
//
#include <hip/hip_runtime.h>
#include <hip/hip_bf16.h>
#include <math.h>

#define BB 16
#define NN 256
#define LL 1024
#define DD 256

constexpr float LN_EPS = 1e-5f;
constexpr float NEG_SLOPE = 0.01f;

typedef __attribute__((ext_vector_type(8))) short short8;
typedef __attribute__((ext_vector_type(4))) float f32x4;
typedef __attribute__((ext_vector_type(4))) int i32x4;

static __device__ __forceinline__ unsigned cvtpk(float lo, float hi) {
  __hip_bfloat162 h = __float22bfloat162_rn(make_float2(lo, hi));
  union { __hip_bfloat162 h; unsigned u; } v; v.h = h;
  return v.u;
}
static __device__ __forceinline__ short8 pack8(float4 f0, float4 f1) {
  union { i32x4 i; short8 s; } v;
  v.i.x = cvtpk(f0.x, f0.y);
  v.i.y = cvtpk(f0.z, f0.w);
  v.i.z = cvtpk(f1.x, f1.y);
  v.i.w = cvtpk(f1.z, f1.w);
  return v.s;
}
static __device__ __forceinline__ unsigned short f2bf(float f) {
  union { float f; unsigned u; } v; v.f = f;
  unsigned r = v.u + 0x7FFFu + ((v.u >> 16) & 1u);
  return (unsigned short)(r >> 16);
}

struct P1 {                               // producer (agemm) LDS
  char atile[64 * 256 * 2];               // 32 KB bf16, XOR-swizzled
  unsigned short sAT[256 * 68];           // 34 KB
  float s2p[8][66];                       // ~2 KB
};
struct P2 {                               // consumer (attn) LDS
  unsigned short sattn[16 * 1024];        // 32 KB, XOR-swizzled
  float ctxp[2][16][DD];                  // 32 KB
  float vp2[2][256];                      // 2 KB
};

// ---------------------------------------------------------------------------
// One kernel, two roles. Blocks 0..255: agemm producer for (b, l-tile).
// Blocks 256..511: attn consumer for (b, n-tile); prelude (v1,c0,s1) runs
// before the per-b spin, so it overlaps producer execution.
// 2 blocks/CU guaranteed (<=128 VGPR via launch_bounds, ~69 KB LDS) -> all
// 512 blocks co-resident -> spin is deadlock-free.
// XCD: producer i and consumer i+256 both land on XCD i&7 = b&7.
// ---------------------------------------------------------------------------
__global__ __launch_bounds__(512, 4) void fused_kernel(
    const float* __restrict__ mol, const float* __restrict__ atom,
    const float* __restrict__ amask, const float* __restrict__ smask,
    const float* __restrict__ W_mol, const float* __restrict__ b_mol,
    const float* __restrict__ W_nb, const float* __restrict__ b_nb,
    const float* __restrict__ align_w, const float* __restrict__ align_b,
    const float* __restrict__ gamma, const float* __restrict__ beta,
    unsigned short* __restrict__ aT, float* __restrict__ s2g,
    unsigned int* __restrict__ cnt, float* __restrict__ out) {
  __shared__ union { P1 p1; P2 p2; } sh;
  __shared__ float v1s[256];
  __shared__ float s1s[16], mu_s[16], rs_s[16];
  __shared__ float c0s;

  int t = threadIdx.x, w = t >> 6, lane = t & 63;
  int lo16 = lane & 15, g = lane >> 4;

  if (blockIdx.x < 256) {
    // =============================== PRODUCER ===============================
    int i = blockIdx.x;
    int x = i & 7, k = i >> 3;
    int b = x + 8 * (k >> 4);
    int l0 = (k & 15) * 64;

    // stage atom tile -> LDS bf16 (swizzled)
    {
      int r = t >> 3, dseg = (t & 7) * 32;
      const float* src = atom + (size_t)(b * LL + l0 + r) * DD + dseg;
      #pragma unroll
      for (int q = 0; q < 4; ++q) {
        float4 f0 = *(const float4*)(src + q * 8);
        float4 f1 = *(const float4*)(src + q * 8 + 4);
        int byte = ((r * 256 + dseg + q * 8) * 2) ^ ((r & 7) << 4);
        *(short8*)(sh.p1.atile + byte) = pack8(f0, f1);
      }
    }
    __syncthreads();

    // MFMA: wave w -> e rows [w*32, w*32+32), all 64 l from LDS
    f32x4 acc[2][4];
    #pragma unroll
    for (int m = 0; m < 2; ++m)
      #pragma unroll
      for (int n = 0; n < 4; ++n) acc[m][n] = f32x4{0.f, 0.f, 0.f, 0.f};

    const float* Ap = W_nb + (size_t)(w * 32 + lo16) * DD + g * 8;
    #pragma unroll 2
    for (int kk = 0; kk < 8; ++kk) {
      short8 af[2];
      #pragma unroll
      for (int m = 0; m < 2; ++m) {
        float4 f0 = *(const float4*)(Ap + m * 16 * DD + kk * 32);
        float4 f1 = *(const float4*)(Ap + m * 16 * DD + kk * 32 + 4);
        af[m] = pack8(f0, f1);
      }
      short8 bf[4];
      #pragma unroll
      for (int n = 0; n < 4; ++n) {
        int l = n * 16 + lo16;
        int byte = ((l * 256 + kk * 32 + g * 8) * 2) ^ ((l & 7) << 4);
        bf[n] = *(const short8*)(sh.p1.atile + byte);
      }
      #pragma unroll
      for (int m = 0; m < 2; ++m)
        #pragma unroll
        for (int n = 0; n < 4; ++n)
          acc[m][n] = __builtin_amdgcn_mfma_f32_16x16x32_bf16(af[m], bf[n],
                                                              acc[m][n], 0, 0, 0);
    }

    // epilogue: +bias -> sAT (bf16); s2 partials from registers
    {
      float4 bias[2], w2r[2];
      #pragma unroll
      for (int m = 0; m < 2; ++m) {
        bias[m] = *(const float4*)&b_nb[w * 32 + m * 16 + g * 4];
        w2r[m] = *(const float4*)&align_w[DD + w * 32 + m * 16 + g * 4];
      }
      float p[4] = {0.f, 0.f, 0.f, 0.f};
      #pragma unroll
      for (int m = 0; m < 2; ++m) {
        #pragma unroll
        for (int n = 0; n < 4; ++n) {
          int l = n * 16 + lo16;
          #pragma unroll
          for (int jj = 0; jj < 4; ++jj) {
            float v = acc[m][n][jj] + ((const float*)&bias[m])[jj];
            sh.p1.sAT[(w * 32 + m * 16 + g * 4 + jj) * 68 + l] = f2bf(v);
            p[n] += ((const float*)&w2r[m])[jj] * v;
          }
        }
      }
      #pragma unroll
      for (int n = 0; n < 4; ++n) {
        p[n] += __shfl_xor(p[n], 16, 64);
        p[n] += __shfl_xor(p[n], 32, 64);
      }
      if (g == 0) {
        #pragma unroll
        for (int n = 0; n < 4; ++n) sh.p1.s2p[w][n * 16 + lo16] = p[n];
      }
    }
    __syncthreads();

    // s2 final sum + store; coalesced aT store
    if (t < 64) {
      float s = 0.f;
      #pragma unroll
      for (int q = 0; q < 8; ++q) s += sh.p1.s2p[q][t];
      s2g[b * LL + l0 + t] = s;
    }
    unsigned short* dst = aT + (size_t)b * DD * LL + l0;
    #pragma unroll
    for (int idx = t; idx < 4096; idx += 512) {
      int e = idx >> 4, ch = idx & 15;
      ushort4 v = *(const ushort4*)&sh.p1.sAT[e * 68 + ch * 4];
      *(ushort4*)(dst + (size_t)e * LL + ch * 4) = v;
    }
    __syncthreads();  // drains vmcnt: all global stores complete

    if (t == 0) {
      __hip_atomic_fetch_add(&cnt[b], 1u, __ATOMIC_RELEASE,
                             __HIP_MEMORY_SCOPE_AGENT);
    }
  } else {
    // =============================== CONSUMER ===============================
    int j = blockIdx.x - 256;
    int x = j & 7, k = j >> 3;
    int b = x + 8 * (k >> 4);
    int n0 = (k & 15) * 16;

    // ---- prelude (independent of producers) ----
    // v1 redundant: thread (d=t&255, eh=t>>8) sums 128 e's
    {
      int d = t & 255, eh = t >> 8;
      float acc = 0.f;
      #pragma unroll 8
      for (int e = eh * 128; e < eh * 128 + 128; ++e)
        acc += align_w[e] * W_mol[e * DD + d];
      sh.p2.vp2[eh][d] = acc;
    }
    if (w == 7) {  // c0
      float s = b_mol[lane] * align_w[lane] +
                b_mol[lane + 64] * align_w[lane + 64] +
                b_mol[lane + 128] * align_w[lane + 128] +
                b_mol[lane + 192] * align_w[lane + 192];
      #pragma unroll
      for (int off = 32; off > 0; off >>= 1) s += __shfl_xor(s, off, 64);
      if (lane == 0) c0s = s + align_b[0];
    }
    __syncthreads();
    if (t < 256) v1s[t] = sh.p2.vp2[0][t] + sh.p2.vp2[1][t];
    __syncthreads();

    // s1: 32 thr/row
    {
      int r = t >> 5, off = (t & 31) * 8;
      const float* mr = mol + (size_t)(b * NN + n0 + r) * DD + off;
      float s = 0.f;
      #pragma unroll
      for (int q = 0; q < 2; ++q) {
        float4 f = *(const float4*)(mr + q * 4);
        s += f.x * v1s[off + q * 4] + f.y * v1s[off + q * 4 + 1] +
             f.z * v1s[off + q * 4 + 2] + f.w * v1s[off + q * 4 + 3];
      }
      s += __shfl_xor(s, 1, 64);
      s += __shfl_xor(s, 2, 64);
      s += __shfl_xor(s, 4, 64);
      s += __shfl_xor(s, 8, 64);
      s += __shfl_xor(s, 16, 64);
      if ((t & 31) == 0) s1s[r] = s + c0s;
    }
    __syncthreads();

    // ---- wait for this b's 16 producers ----
    if (t == 0) {
      while (__hip_atomic_load(&cnt[b], __ATOMIC_ACQUIRE,
                               __HIP_MEMORY_SCOPE_AGENT) < 16u) {
        __builtin_amdgcn_s_sleep(8);
      }
      __threadfence();
    }
    __syncthreads();

    // ---- softmax: wave w -> rows 2w, 2w+1 ----
    {
      float s2v[16], amv[16], smv[16];
      #pragma unroll
      for (int q = 0; q < 16; ++q) {
        int l = lane + 64 * q;
        s2v[q] = s2g[b * LL + l];
        amv[q] = amask[b * LL + l];
        smv[q] = smask[b * LL + l];
      }
      #pragma unroll
      for (int rr = 0; rr < 2; ++rr) {
        int r = w * 2 + rr;
        float s1v = s1s[r];
        float p[16];
        float mx = -INFINITY;
        #pragma unroll
        for (int q = 0; q < 16; ++q) {
          float sc = s1v + s2v[q];
          sc = sc > 0.f ? sc : NEG_SLOPE * sc;
          sc += smv[q];
          p[q] = sc;
          mx = fmaxf(mx, sc);
        }
        #pragma unroll
        for (int off = 32; off > 0; off >>= 1) mx = fmaxf(mx, __shfl_xor(mx, off, 64));
        float sum = 0.f;
        #pragma unroll
        for (int q = 0; q < 16; ++q) {
          p[q] = __expf(p[q] - mx);
          sum += p[q];
        }
        #pragma unroll
        for (int off = 32; off > 0; off >>= 1) sum += __shfl_xor(sum, off, 64);
        float inv = 1.f / sum;
        #pragma unroll
        for (int q = 0; q < 16; ++q) {
          unsigned short bv = f2bf(p[q] * amv[q] * inv);
          int l = lane + 64 * q;
          int byte = ((r * 1024 + l) * 2) ^ ((r & 7) << 4);
          *(unsigned short*)((char*)sh.p2.sattn + byte) = bv;
        }
      }
    }
    __syncthreads();

    // ---- PV MFMA: wave = e-quadrant (w&3) x l-half (w>>2) ----
    {
      int e0 = (w & 3) * 64, lh = w >> 2;
      f32x4 acc[4];
      #pragma unroll
      for (int n = 0; n < 4; ++n) acc[n] = f32x4{0.f, 0.f, 0.f, 0.f};
      const unsigned short* Bp =
          aT + (size_t)b * DD * LL + (size_t)(e0 + lo16) * LL + lh * 512 + g * 8;
      #pragma unroll 4
      for (int kk = 0; kk < 16; ++kk) {
        short8 afr = *(const short8*)((const char*)sh.p2.sattn +
            (((lo16 * 1024 + lh * 512 + kk * 32 + g * 8) * 2) ^ ((lo16 & 7) << 4)));
        #pragma unroll
        for (int n = 0; n < 4; ++n) {
          short8 bfr = *(const short8*)(Bp + (size_t)n * 16 * LL + kk * 32);
          acc[n] = __builtin_amdgcn_mfma_f32_16x16x32_bf16(afr, bfr, acc[n], 0, 0, 0);
        }
      }
      #pragma unroll
      for (int n = 0; n < 4; ++n)
        #pragma unroll
        for (int jj = 0; jj < 4; ++jj)
          sh.p2.ctxp[lh][g * 4 + jj][e0 + n * 16 + lo16] = acc[n][jj];
    }
    __syncthreads();

    // ---- LN stats: wave w -> rows 2w, 2w+1 ----
    #pragma unroll
    for (int rr = 0; rr < 2; ++rr) {
      int r = w * 2 + rr;
      float s = 0.f, sq = 0.f;
      #pragma unroll
      for (int jj = 0; jj < 4; ++jj) {
        int cc = lane + 64 * jj;
        float v = sh.p2.ctxp[0][r][cc] + sh.p2.ctxp[1][r][cc];
        s += v;
        sq += v * v;
      }
      #pragma unroll
      for (int off = 32; off > 0; off >>= 1) {
        s += __shfl_xor(s, off, 64);
        sq += __shfl_xor(sq, off, 64);
      }
      if (lane == 0) {
        float mu = s * (1.f / 256.f);
        float var = sq * (1.f / 256.f) - mu * mu;
        mu_s[r] = mu;
        rs_s[r] = rsqrtf(var + LN_EPS);
      }
    }
    __syncthreads();

    // ---- store ----
    #pragma unroll
    for (int q = 0; q < 8; ++q) {
      int idx = t + 512 * q;
      int r = idx >> 8, d = idx & 255;
      float v = sh.p2.ctxp[0][r][d] + sh.p2.ctxp[1][r][d];
      out[(size_t)(b * NN + n0 + r) * DD + d] =
          (v - mu_s[r]) * rs_s[r] * gamma[d] + beta[d];
    }
  }
}

// ---------------------------------------------------------------------------
extern "C" void kernel_launch(void* const* d_in, const int* in_sizes, int n_in,
                              void* d_out, int out_size, void* d_ws, size_t ws_size,
                              hipStream_t stream) {
  const float* mol     = (const float*)d_in[0];
  const float* atom    = (const float*)d_in[1];
  const float* amask   = (const float*)d_in[2];
  const float* smask   = (const float*)d_in[3];
  const float* W_mol   = (const float*)d_in[4];
  const float* b_mol   = (const float*)d_in[5];
  const float* W_nb    = (const float*)d_in[6];
  const float* b_nb    = (const float*)d_in[7];
  const float* align_w = (const float*)d_in[8];
  const float* align_b = (const float*)d_in[9];
  const float* gamma   = (const float*)d_in[10];
  const float* beta    = (const float*)d_in[11];
  float* outp = (float*)d_out;

  char* wsb = (char*)d_ws;
  unsigned short* aT = (unsigned short*)wsb;                    // 8 MB
  float* s2g = (float*)(wsb + 8388608);                         // 64 KB
  unsigned int* cnt = (unsigned int*)(wsb + 8388608 + 65536);   // 64 B

  hipMemsetAsync(cnt, 0, 16 * sizeof(unsigned int), stream);
  fused_kernel<<<512, 512, 0, stream>>>(mol, atom, amask, smask, W_mol, b_mol,
                                        W_nb, b_nb, align_w, align_b, gamma,
                                        beta, aT, s2g, cnt, outp);
}

// Round 12
// 44.849 us; speedup vs baseline: 1.2579x; 1.2579x over previous
//
#include <hip/hip_runtime.h>
#include <hip/hip_bf16.h>
#include <math.h>

#define BB 16
#define NN 256
#define LL 1024
#define DD 256

constexpr float LN_EPS = 1e-5f;
constexpr float NEG_SLOPE = 0.01f;

typedef __attribute__((ext_vector_type(8))) short short8;
typedef __attribute__((ext_vector_type(4))) float f32x4;
typedef __attribute__((ext_vector_type(4))) int i32x4;

static __device__ __forceinline__ unsigned cvtpk(float lo, float hi) {
  __hip_bfloat162 h = __float22bfloat162_rn(make_float2(lo, hi));
  union { __hip_bfloat162 h; unsigned u; } v; v.h = h;
  return v.u;
}
static __device__ __forceinline__ short8 pack8(float4 f0, float4 f1) {
  union { i32x4 i; short8 s; } v;
  v.i.x = cvtpk(f0.x, f0.y);
  v.i.y = cvtpk(f0.z, f0.w);
  v.i.z = cvtpk(f1.x, f1.y);
  v.i.w = cvtpk(f1.z, f1.w);
  return v.s;
}
static __device__ __forceinline__ unsigned short f2bf(float f) {
  union { float f; unsigned u; } v; v.f = f;
  unsigned r = v.u + 0x7FFFu + ((v.u >> 16) & 1u);
  return (unsigned short)(r >> 16);
}

// ---------------------------------------------------------------------------
// agemm (MFMA): aT[b][e][l] = sum_d W_nb[e,d]*atom[b,l,d] + b_nb[e]  (bf16)
//   + s2[b][l] from the f32 accumulators (register route, conflict-free)
//   + blocks 0..15 side-job: v1 columns; block 0: c0.
// 512 blocks x 512 thr (8 waves). Block tile 256e x 32l -> 38 KB LDS ->
// 2 resident blocks/CU (grid was the occupancy limit at 256).
// Wave w: e in [w*32, w*32+32), all 32 l (W_nb read exactly once per block).
// XCD swizzle: all 32 blocks of batch b on XCD b&7.
// ---------------------------------------------------------------------------
__global__ __launch_bounds__(512) void agemm_kernel(
    const float* __restrict__ atom, const float* __restrict__ W_nb,
    const float* __restrict__ b_nb, const float* __restrict__ W_mol,
    const float* __restrict__ b_mol, const float* __restrict__ align_w,
    const float* __restrict__ align_b, unsigned short* __restrict__ aT,
    float* __restrict__ s2g, float* __restrict__ v1c) {
  __shared__ char atile[32 * 256 * 2];      // 16 KB bf16, XOR-swizzled
  __shared__ unsigned short sAT[256 * 36];  // 18 KB (stride 36 shorts)
  __shared__ float vp[32][16];
  __shared__ float s2p[8][34];              // padded, conflict-free

  int t = threadIdx.x;
  int w = t >> 6, lane = t & 63;
  int i = blockIdx.x;
  int x = i & 7, k = i >> 3;          // k in 0..63
  int b = x + 8 * (k >> 5);           // 32 blocks per b, all on XCD b&7
  int l0 = (k & 31) * 32;
  int lo16 = lane & 15, g = lane >> 4;

  // ---- stage atom tile -> LDS bf16 (swizzled) ----
  {
    int r = t >> 4, dseg = (t & 15) * 16;
    const float* src = atom + (size_t)(b * LL + l0 + r) * DD + dseg;
    #pragma unroll
    for (int q = 0; q < 2; ++q) {
      float4 f0 = *(const float4*)(src + q * 8);
      float4 f1 = *(const float4*)(src + q * 8 + 4);
      int byte = ((r * 256 + dseg + q * 8) * 2) ^ ((r & 7) << 4);
      *(short8*)(atile + byte) = pack8(f0, f1);
    }
  }

  // ---- side job: v1 columns (blocks 0..15), c0 (block 0) ----
  if (i < 16) {
    int d0 = i * 16;
    int dl = t & 15, eseg = t >> 4;
    float acc = 0.f;
    #pragma unroll
    for (int q = 0; q < 8; ++q) {
      int e = eseg * 8 + q;
      acc += align_w[e] * W_mol[e * DD + d0 + dl];
    }
    vp[eseg][dl] = acc;
    __syncthreads();
    if (t < 16) {
      float s = 0.f;
      #pragma unroll
      for (int q = 0; q < 32; ++q) s += vp[q][t];
      v1c[d0 + t] = s;
    }
    if (i == 0 && w == 1) {
      float s = b_mol[lane] * align_w[lane] +
                b_mol[lane + 64] * align_w[lane + 64] +
                b_mol[lane + 128] * align_w[lane + 128] +
                b_mol[lane + 192] * align_w[lane + 192];
      #pragma unroll
      for (int off = 32; off > 0; off >>= 1) s += __shfl_xor(s, off, 64);
      if (lane == 0) v1c[256] = s + align_b[0];
    }
  }
  __syncthreads();

  // ---- MFMA: wave w -> e rows [w*32, w*32+32), all 32 l from LDS ----
  f32x4 acc[2][2];
  #pragma unroll
  for (int m = 0; m < 2; ++m)
    #pragma unroll
    for (int n = 0; n < 2; ++n) acc[m][n] = f32x4{0.f, 0.f, 0.f, 0.f};

  const float* Ap = W_nb + (size_t)(w * 32 + lo16) * DD + g * 8;

  #pragma unroll 4
  for (int kk = 0; kk < 8; ++kk) {
    short8 af[2];
    #pragma unroll
    for (int m = 0; m < 2; ++m) {
      float4 f0 = *(const float4*)(Ap + m * 16 * DD + kk * 32);
      float4 f1 = *(const float4*)(Ap + m * 16 * DD + kk * 32 + 4);
      af[m] = pack8(f0, f1);
    }
    short8 bf[2];
    #pragma unroll
    for (int n = 0; n < 2; ++n) {
      int l = n * 16 + lo16;
      int byte = ((l * 256 + kk * 32 + g * 8) * 2) ^ ((l & 7) << 4);
      bf[n] = *(const short8*)(atile + byte);
    }
    #pragma unroll
    for (int m = 0; m < 2; ++m)
      #pragma unroll
      for (int n = 0; n < 2; ++n)
        acc[m][n] = __builtin_amdgcn_mfma_f32_16x16x32_bf16(af[m], bf[n],
                                                            acc[m][n], 0, 0, 0);
  }

  // ---- epilogue: +bias -> sAT (bf16); s2 partials from registers ----
  {
    float4 bias[2], w2r[2];
    #pragma unroll
    for (int m = 0; m < 2; ++m) {
      bias[m] = *(const float4*)&b_nb[w * 32 + m * 16 + g * 4];
      w2r[m] = *(const float4*)&align_w[DD + w * 32 + m * 16 + g * 4];
    }
    float p[2] = {0.f, 0.f};
    #pragma unroll
    for (int m = 0; m < 2; ++m) {
      #pragma unroll
      for (int n = 0; n < 2; ++n) {
        int l = n * 16 + lo16;
        #pragma unroll
        for (int jj = 0; jj < 4; ++jj) {
          float v = acc[m][n][jj] + ((const float*)&bias[m])[jj];
          sAT[(w * 32 + m * 16 + g * 4 + jj) * 36 + l] = f2bf(v);
          p[n] += ((const float*)&w2r[m])[jj] * v;
        }
      }
    }
    #pragma unroll
    for (int n = 0; n < 2; ++n) {
      p[n] += __shfl_xor(p[n], 16, 64);
      p[n] += __shfl_xor(p[n], 32, 64);
    }
    if (g == 0) {
      #pragma unroll
      for (int n = 0; n < 2; ++n) s2p[w][n * 16 + lo16] = p[n];
    }
  }
  __syncthreads();

  // ---- s2 final sum over 8 waves (conflict-free) + store ----
  if (t < 32) {
    float s = 0.f;
    #pragma unroll
    for (int q = 0; q < 8; ++q) s += s2p[q][t];
    s2g[b * LL + l0 + t] = s;
  }
  // ---- coalesced store to aT ----
  unsigned short* dst = aT + (size_t)b * DD * LL + l0;
  #pragma unroll
  for (int idx = t; idx < 2048; idx += 512) {
    int e = idx >> 3, ch = idx & 7;
    ushort4 v = *(const ushort4*)&sAT[e * 36 + ch * 4];
    *(ushort4*)(dst + (size_t)e * LL + ch * 4) = v;
  }
}

// ---------------------------------------------------------------------------
// attn: block = (b, 16 n-rows), 512 thr = 8 waves. XCD swizzle (b&7).
// (Byte-identical to the 39.3 µs round-10 version.)
// ---------------------------------------------------------------------------
__global__ __launch_bounds__(512) void attn_kernel(
    const unsigned short* __restrict__ aT, const float* __restrict__ mol,
    const float* __restrict__ v1c, const float* __restrict__ s2,
    const float* __restrict__ amask, const float* __restrict__ smask,
    const float* __restrict__ gamma, const float* __restrict__ beta,
    float* __restrict__ out) {
  __shared__ unsigned short sattn[16 * 1024];  // 32 KB, XOR-swizzled
  __shared__ float ctxp[2][16][DD];            // 32 KB
  __shared__ float v1s[256];
  __shared__ float s1s[16];
  __shared__ float mu_s[16], rs_s[16];
  int i = blockIdx.x;
  int x = i & 7, k = i >> 3;
  int b = x + 8 * (k >> 4);
  int n0 = (k & 15) * 16;
  int t = threadIdx.x, w = t >> 6, lane = t & 63;

  float c0 = v1c[256];
  if (t < 256) v1s[t] = v1c[t];
  __syncthreads();

  // ---- s1: 32 thr/row ----
  {
    int r = t >> 5, off = (t & 31) * 8;
    const float* mr = mol + (size_t)(b * NN + n0 + r) * DD + off;
    float s = 0.f;
    #pragma unroll
    for (int q = 0; q < 2; ++q) {
      float4 f = *(const float4*)(mr + q * 4);
      s += f.x * v1s[off + q * 4] + f.y * v1s[off + q * 4 + 1] +
           f.z * v1s[off + q * 4 + 2] + f.w * v1s[off + q * 4 + 3];
    }
    s += __shfl_xor(s, 1, 64);
    s += __shfl_xor(s, 2, 64);
    s += __shfl_xor(s, 4, 64);
    s += __shfl_xor(s, 8, 64);
    s += __shfl_xor(s, 16, 64);
    if ((t & 31) == 0) s1s[r] = s + c0;
  }
  __syncthreads();

  // ---- softmax: wave w -> rows 2w, 2w+1 ----
  {
    float s2v[16], amv[16], smv[16];
    #pragma unroll
    for (int q = 0; q < 16; ++q) {
      int l = lane + 64 * q;
      s2v[q] = s2[b * LL + l];
      amv[q] = amask[b * LL + l];
      smv[q] = smask[b * LL + l];
    }
    #pragma unroll
    for (int rr = 0; rr < 2; ++rr) {
      int r = w * 2 + rr;
      float s1v = s1s[r];
      float p[16];
      float mx = -INFINITY;
      #pragma unroll
      for (int q = 0; q < 16; ++q) {
        float sc = s1v + s2v[q];
        sc = sc > 0.f ? sc : NEG_SLOPE * sc;
        sc += smv[q];
        p[q] = sc;
        mx = fmaxf(mx, sc);
      }
      #pragma unroll
      for (int off = 32; off > 0; off >>= 1) mx = fmaxf(mx, __shfl_xor(mx, off, 64));
      float sum = 0.f;
      #pragma unroll
      for (int q = 0; q < 16; ++q) {
        p[q] = __expf(p[q] - mx);
        sum += p[q];
      }
      #pragma unroll
      for (int off = 32; off > 0; off >>= 1) sum += __shfl_xor(sum, off, 64);
      float inv = 1.f / sum;
      #pragma unroll
      for (int q = 0; q < 16; ++q) {
        unsigned short bv = f2bf(p[q] * amv[q] * inv);
        int l = lane + 64 * q;
        int byte = ((r * 1024 + l) * 2) ^ ((r & 7) << 4);
        *(unsigned short*)((char*)sattn + byte) = bv;
      }
    }
  }
  __syncthreads();

  // ---- PV MFMA: wave = e-quadrant (w&3) x l-half (w>>2) ----
  int lo16 = lane & 15, g = lane >> 4;
  {
    int e0 = (w & 3) * 64, lh = w >> 2;
    f32x4 acc[4];
    #pragma unroll
    for (int n = 0; n < 4; ++n) acc[n] = f32x4{0.f, 0.f, 0.f, 0.f};
    const unsigned short* Bp =
        aT + (size_t)b * DD * LL + (size_t)(e0 + lo16) * LL + lh * 512 + g * 8;
    #pragma unroll 4
    for (int kk = 0; kk < 16; ++kk) {
      short8 afr = *(const short8*)((const char*)sattn +
          (((lo16 * 1024 + lh * 512 + kk * 32 + g * 8) * 2) ^ ((lo16 & 7) << 4)));
      #pragma unroll
      for (int n = 0; n < 4; ++n) {
        short8 bfr = *(const short8*)(Bp + (size_t)n * 16 * LL + kk * 32);
        acc[n] = __builtin_amdgcn_mfma_f32_16x16x32_bf16(afr, bfr, acc[n], 0, 0, 0);
      }
    }
    #pragma unroll
    for (int n = 0; n < 4; ++n)
      #pragma unroll
      for (int jj = 0; jj < 4; ++jj)
        ctxp[lh][g * 4 + jj][e0 + n * 16 + lo16] = acc[n][jj];
  }
  __syncthreads();

  // ---- LN stats: wave w -> rows 2w, 2w+1 ----
  #pragma unroll
  for (int rr = 0; rr < 2; ++rr) {
    int r = w * 2 + rr;
    float s = 0.f, sq = 0.f;
    #pragma unroll
    for (int jj = 0; jj < 4; ++jj) {
      int cc = lane + 64 * jj;
      float v = ctxp[0][r][cc] + ctxp[1][r][cc];
      s += v;
      sq += v * v;
    }
    #pragma unroll
    for (int off = 32; off > 0; off >>= 1) {
      s += __shfl_xor(s, off, 64);
      sq += __shfl_xor(sq, off, 64);
    }
    if (lane == 0) {
      float mu = s * (1.f / 256.f);
      float var = sq * (1.f / 256.f) - mu * mu;
      mu_s[r] = mu;
      rs_s[r] = rsqrtf(var + LN_EPS);
    }
  }
  __syncthreads();

  // ---- store ----
  #pragma unroll
  for (int q = 0; q < 8; ++q) {
    int idx = t + 512 * q;
    int r = idx >> 8, d = idx & 255;
    float v = ctxp[0][r][d] + ctxp[1][r][d];
    out[(size_t)(b * NN + n0 + r) * DD + d] =
        (v - mu_s[r]) * rs_s[r] * gamma[d] + beta[d];
  }
}

// ---------------------------------------------------------------------------
extern "C" void kernel_launch(void* const* d_in, const int* in_sizes, int n_in,
                              void* d_out, int out_size, void* d_ws, size_t ws_size,
                              hipStream_t stream) {
  const float* mol     = (const float*)d_in[0];
  const float* atom    = (const float*)d_in[1];
  const float* amask   = (const float*)d_in[2];
  const float* smask   = (const float*)d_in[3];
  const float* W_mol   = (const float*)d_in[4];
  const float* b_mol   = (const float*)d_in[5];
  const float* W_nb    = (const float*)d_in[6];
  const float* b_nb    = (const float*)d_in[7];
  const float* align_w = (const float*)d_in[8];
  const float* align_b = (const float*)d_in[9];
  const float* gamma   = (const float*)d_in[10];
  const float* beta    = (const float*)d_in[11];
  float* outp = (float*)d_out;

  char* wsb = (char*)d_ws;
  unsigned short* aT = (unsigned short*)wsb;          // 8 MB
  float* s2g = (float*)(wsb + 8388608);               // 64 KB
  float* v1c = s2g + BB * LL;                         // 257 floats

  agemm_kernel<<<512, 512, 0, stream>>>(atom, W_nb, b_nb, W_mol, b_mol,
                                        align_w, align_b, aT, s2g, v1c);
  attn_kernel<<<256, 512, 0, stream>>>(aT, mol, v1c, s2g, amask, smask,
                                       gamma, beta, outp);
}

// Round 13
// 39.541 us; speedup vs baseline: 1.4268x; 1.1342x over previous
//
#include <hip/hip_runtime.h>
#include <hip/hip_bf16.h>
#include <math.h>

#define BB 16
#define NN 256
#define LL 1024
#define DD 256

constexpr float LN_EPS = 1e-5f;
constexpr float NEG_SLOPE = 0.01f;

typedef __attribute__((ext_vector_type(8))) short short8;
typedef __attribute__((ext_vector_type(4))) float f32x4;
typedef __attribute__((ext_vector_type(4))) int i32x4;

static __device__ __forceinline__ unsigned cvtpk(float lo, float hi) {
  __hip_bfloat162 h = __float22bfloat162_rn(make_float2(lo, hi));
  union { __hip_bfloat162 h; unsigned u; } v; v.h = h;
  return v.u;
}
static __device__ __forceinline__ short8 pack8(float4 f0, float4 f1) {
  union { i32x4 i; short8 s; } v;
  v.i.x = cvtpk(f0.x, f0.y);
  v.i.y = cvtpk(f0.z, f0.w);
  v.i.z = cvtpk(f1.x, f1.y);
  v.i.w = cvtpk(f1.z, f1.w);
  return v.s;
}
static __device__ __forceinline__ unsigned short f2bf(float f) {
  union { float f; unsigned u; } v; v.f = f;
  unsigned r = v.u + 0x7FFFu + ((v.u >> 16) & 1u);
  return (unsigned short)(r >> 16);
}

// ---------------------------------------------------------------------------
// agemm (MFMA): aT[b][e][l] = sum_d W_nb[e,d]*atom[b,l,d] + b_nb[e]  (bf16)
//   + s2[b][l] from the f32 accumulators (register route, conflict-free)
//   + blocks 0..15 side-job: v1 columns; block 0: c0.
// 256 blocks x 512 thr (8 waves). Block tile 256e x 64l.
// Wave w: e in [w*32, w*32+32), ALL 64 l (W_nb read exactly once per block).
// Atom tile staged bf16 in LDS once (XOR swizzle).
// XCD swizzle: all blocks of batch b on XCD b&7.
// ---------------------------------------------------------------------------
__global__ __launch_bounds__(512) void agemm_kernel(
    const float* __restrict__ atom, const float* __restrict__ W_nb,
    const float* __restrict__ b_nb, const float* __restrict__ W_mol,
    const float* __restrict__ b_mol, const float* __restrict__ align_w,
    const float* __restrict__ align_b, unsigned short* __restrict__ aT,
    float* __restrict__ s2g, float* __restrict__ v1c) {
  __shared__ char atile[64 * 256 * 2];      // 32 KB bf16, XOR-swizzled
  __shared__ unsigned short sAT[256 * 68];  // 34 KB
  __shared__ float vp[32][16];
  __shared__ float s2p[8][66];              // padded, conflict-free

  int t = threadIdx.x;
  int w = t >> 6, lane = t & 63;
  int i = blockIdx.x;
  int x = i & 7, k = i >> 3;
  int b = x + 8 * (k >> 4);          // all blocks of b on XCD b&7
  int l0 = (k & 15) * 64;
  int lo16 = lane & 15, g = lane >> 4;

  // ---- stage atom tile -> LDS bf16 (swizzled) ----
  {
    int r = t >> 3, dseg = (t & 7) * 32;
    const float* src = atom + (size_t)(b * LL + l0 + r) * DD + dseg;
    #pragma unroll
    for (int q = 0; q < 4; ++q) {
      float4 f0 = *(const float4*)(src + q * 8);
      float4 f1 = *(const float4*)(src + q * 8 + 4);
      int byte = ((r * 256 + dseg + q * 8) * 2) ^ ((r & 7) << 4);
      *(short8*)(atile + byte) = pack8(f0, f1);
    }
  }

  // ---- side job: v1 columns (blocks 0..15), c0 (block 0) ----
  if (i < 16) {
    int d0 = i * 16;
    int dl = t & 15, eseg = t >> 4;
    float acc = 0.f;
    #pragma unroll
    for (int q = 0; q < 8; ++q) {
      int e = eseg * 8 + q;
      acc += align_w[e] * W_mol[e * DD + d0 + dl];
    }
    vp[eseg][dl] = acc;
    __syncthreads();
    if (t < 16) {
      float s = 0.f;
      #pragma unroll
      for (int q = 0; q < 32; ++q) s += vp[q][t];
      v1c[d0 + t] = s;
    }
    if (i == 0 && w == 1) {
      float s = b_mol[lane] * align_w[lane] +
                b_mol[lane + 64] * align_w[lane + 64] +
                b_mol[lane + 128] * align_w[lane + 128] +
                b_mol[lane + 192] * align_w[lane + 192];
      #pragma unroll
      for (int off = 32; off > 0; off >>= 1) s += __shfl_xor(s, off, 64);
      if (lane == 0) v1c[256] = s + align_b[0];
    }
  }
  __syncthreads();

  // ---- MFMA: wave w -> e rows [w*32, w*32+32), all 64 l from LDS ----
  f32x4 acc[2][4];
  #pragma unroll
  for (int m = 0; m < 2; ++m)
    #pragma unroll
    for (int n = 0; n < 4; ++n) acc[m][n] = f32x4{0.f, 0.f, 0.f, 0.f};

  const float* Ap = W_nb + (size_t)(w * 32 + lo16) * DD + g * 8;

  #pragma unroll 4
  for (int kk = 0; kk < 8; ++kk) {
    short8 af[2];
    #pragma unroll
    for (int m = 0; m < 2; ++m) {
      float4 f0 = *(const float4*)(Ap + m * 16 * DD + kk * 32);
      float4 f1 = *(const float4*)(Ap + m * 16 * DD + kk * 32 + 4);
      af[m] = pack8(f0, f1);
    }
    short8 bf[4];
    #pragma unroll
    for (int n = 0; n < 4; ++n) {
      int l = n * 16 + lo16;
      int byte = ((l * 256 + kk * 32 + g * 8) * 2) ^ ((l & 7) << 4);
      bf[n] = *(const short8*)(atile + byte);
    }
    #pragma unroll
    for (int m = 0; m < 2; ++m)
      #pragma unroll
      for (int n = 0; n < 4; ++n)
        acc[m][n] = __builtin_amdgcn_mfma_f32_16x16x32_bf16(af[m], bf[n],
                                                            acc[m][n], 0, 0, 0);
  }

  // ---- epilogue: +bias -> sAT (bf16); s2 partials from registers ----
  {
    float4 bias[2], w2r[2];
    #pragma unroll
    for (int m = 0; m < 2; ++m) {
      bias[m] = *(const float4*)&b_nb[w * 32 + m * 16 + g * 4];
      w2r[m] = *(const float4*)&align_w[DD + w * 32 + m * 16 + g * 4];
    }
    float p[4] = {0.f, 0.f, 0.f, 0.f};
    #pragma unroll
    for (int m = 0; m < 2; ++m) {
      #pragma unroll
      for (int n = 0; n < 4; ++n) {
        int l = n * 16 + lo16;
        #pragma unroll
        for (int jj = 0; jj < 4; ++jj) {
          float v = acc[m][n][jj] + ((const float*)&bias[m])[jj];
          sAT[(w * 32 + m * 16 + g * 4 + jj) * 68 + l] = f2bf(v);
          p[n] += ((const float*)&w2r[m])[jj] * v;
        }
      }
    }
    #pragma unroll
    for (int n = 0; n < 4; ++n) {
      p[n] += __shfl_xor(p[n], 16, 64);
      p[n] += __shfl_xor(p[n], 32, 64);
    }
    if (g == 0) {
      #pragma unroll
      for (int n = 0; n < 4; ++n) s2p[w][n * 16 + lo16] = p[n];
    }
  }
  __syncthreads();

  // ---- s2 final sum over 8 waves (conflict-free) + store ----
  if (t < 64) {
    float s = 0.f;
    #pragma unroll
    for (int q = 0; q < 8; ++q) s += s2p[q][t];
    s2g[b * LL + l0 + t] = s;
  }
  // ---- coalesced store to aT ----
  unsigned short* dst = aT + (size_t)b * DD * LL + l0;
  #pragma unroll
  for (int idx = t; idx < 4096; idx += 512) {
    int e = idx >> 4, ch = idx & 15;
    ushort4 v = *(const ushort4*)&sAT[e * 68 + ch * 4];
    *(ushort4*)(dst + (size_t)e * LL + ch * 4) = v;
  }
}

// ---------------------------------------------------------------------------
// attn: block = (b, 16 n-rows), 512 thr = 8 waves. XCD swizzle (b&7).
// R10 version + ctxp row pad 256->260 (kills 4-way bank conflict on the
// fragment scatter-store) + deeper PV unroll.
// ---------------------------------------------------------------------------
__global__ __launch_bounds__(512) void attn_kernel(
    const unsigned short* __restrict__ aT, const float* __restrict__ mol,
    const float* __restrict__ v1c, const float* __restrict__ s2,
    const float* __restrict__ amask, const float* __restrict__ smask,
    const float* __restrict__ gamma, const float* __restrict__ beta,
    float* __restrict__ out) {
  __shared__ unsigned short sattn[16 * 1024];  // 32 KB, XOR-swizzled
  __shared__ float ctxp[2][16][260];           // 33.3 KB, padded rows
  __shared__ float v1s[256];
  __shared__ float s1s[16];
  __shared__ float mu_s[16], rs_s[16];
  int i = blockIdx.x;
  int x = i & 7, k = i >> 3;
  int b = x + 8 * (k >> 4);
  int n0 = (k & 15) * 16;
  int t = threadIdx.x, w = t >> 6, lane = t & 63;

  float c0 = v1c[256];
  if (t < 256) v1s[t] = v1c[t];
  __syncthreads();

  // ---- s1: 32 thr/row ----
  {
    int r = t >> 5, off = (t & 31) * 8;
    const float* mr = mol + (size_t)(b * NN + n0 + r) * DD + off;
    float s = 0.f;
    #pragma unroll
    for (int q = 0; q < 2; ++q) {
      float4 f = *(const float4*)(mr + q * 4);
      s += f.x * v1s[off + q * 4] + f.y * v1s[off + q * 4 + 1] +
           f.z * v1s[off + q * 4 + 2] + f.w * v1s[off + q * 4 + 3];
    }
    s += __shfl_xor(s, 1, 64);
    s += __shfl_xor(s, 2, 64);
    s += __shfl_xor(s, 4, 64);
    s += __shfl_xor(s, 8, 64);
    s += __shfl_xor(s, 16, 64);
    if ((t & 31) == 0) s1s[r] = s + c0;
  }
  __syncthreads();

  // ---- softmax: wave w -> rows 2w, 2w+1 ----
  {
    float s2v[16], amv[16], smv[16];
    #pragma unroll
    for (int q = 0; q < 16; ++q) {
      int l = lane + 64 * q;
      s2v[q] = s2[b * LL + l];
      amv[q] = amask[b * LL + l];
      smv[q] = smask[b * LL + l];
    }
    #pragma unroll
    for (int rr = 0; rr < 2; ++rr) {
      int r = w * 2 + rr;
      float s1v = s1s[r];
      float p[16];
      float mx = -INFINITY;
      #pragma unroll
      for (int q = 0; q < 16; ++q) {
        float sc = s1v + s2v[q];
        sc = sc > 0.f ? sc : NEG_SLOPE * sc;
        sc += smv[q];
        p[q] = sc;
        mx = fmaxf(mx, sc);
      }
      #pragma unroll
      for (int off = 32; off > 0; off >>= 1) mx = fmaxf(mx, __shfl_xor(mx, off, 64));
      float sum = 0.f;
      #pragma unroll
      for (int q = 0; q < 16; ++q) {
        p[q] = __expf(p[q] - mx);
        sum += p[q];
      }
      #pragma unroll
      for (int off = 32; off > 0; off >>= 1) sum += __shfl_xor(sum, off, 64);
      float inv = 1.f / sum;
      #pragma unroll
      for (int q = 0; q < 16; ++q) {
        unsigned short bv = f2bf(p[q] * amv[q] * inv);
        int l = lane + 64 * q;
        int byte = ((r * 1024 + l) * 2) ^ ((r & 7) << 4);
        *(unsigned short*)((char*)sattn + byte) = bv;
      }
    }
  }
  __syncthreads();

  // ---- PV MFMA: wave = e-quadrant (w&3) x l-half (w>>2) ----
  int lo16 = lane & 15, g = lane >> 4;
  {
    int e0 = (w & 3) * 64, lh = w >> 2;
    f32x4 acc[4];
    #pragma unroll
    for (int n = 0; n < 4; ++n) acc[n] = f32x4{0.f, 0.f, 0.f, 0.f};
    const unsigned short* Bp =
        aT + (size_t)b * DD * LL + (size_t)(e0 + lo16) * LL + lh * 512 + g * 8;
    #pragma unroll 8
    for (int kk = 0; kk < 16; ++kk) {
      short8 afr = *(const short8*)((const char*)sattn +
          (((lo16 * 1024 + lh * 512 + kk * 32 + g * 8) * 2) ^ ((lo16 & 7) << 4)));
      #pragma unroll
      for (int n = 0; n < 4; ++n) {
        short8 bfr = *(const short8*)(Bp + (size_t)n * 16 * LL + kk * 32);
        acc[n] = __builtin_amdgcn_mfma_f32_16x16x32_bf16(afr, bfr, acc[n], 0, 0, 0);
      }
    }
    #pragma unroll
    for (int n = 0; n < 4; ++n)
      #pragma unroll
      for (int jj = 0; jj < 4; ++jj)
        ctxp[lh][g * 4 + jj][e0 + n * 16 + lo16] = acc[n][jj];
  }
  __syncthreads();

  // ---- LN stats: wave w -> rows 2w, 2w+1 ----
  #pragma unroll
  for (int rr = 0; rr < 2; ++rr) {
    int r = w * 2 + rr;
    float s = 0.f, sq = 0.f;
    #pragma unroll
    for (int jj = 0; jj < 4; ++jj) {
      int cc = lane + 64 * jj;
      float v = ctxp[0][r][cc] + ctxp[1][r][cc];
      s += v;
      sq += v * v;
    }
    #pragma unroll
    for (int off = 32; off > 0; off >>= 1) {
      s += __shfl_xor(s, off, 64);
      sq += __shfl_xor(sq, off, 64);
    }
    if (lane == 0) {
      float mu = s * (1.f / 256.f);
      float var = sq * (1.f / 256.f) - mu * mu;
      mu_s[r] = mu;
      rs_s[r] = rsqrtf(var + LN_EPS);
    }
  }
  __syncthreads();

  // ---- store ----
  #pragma unroll
  for (int q = 0; q < 8; ++q) {
    int idx = t + 512 * q;
    int r = idx >> 8, d = idx & 255;
    float v = ctxp[0][r][d] + ctxp[1][r][d];
    out[(size_t)(b * NN + n0 + r) * DD + d] =
        (v - mu_s[r]) * rs_s[r] * gamma[d] + beta[d];
  }
}

// ---------------------------------------------------------------------------
extern "C" void kernel_launch(void* const* d_in, const int* in_sizes, int n_in,
                              void* d_out, int out_size, void* d_ws, size_t ws_size,
                              hipStream_t stream) {
  const float* mol     = (const float*)d_in[0];
  const float* atom    = (const float*)d_in[1];
  const float* amask   = (const float*)d_in[2];
  const float* smask   = (const float*)d_in[3];
  const float* W_mol   = (const float*)d_in[4];
  const float* b_mol   = (const float*)d_in[5];
  const float* W_nb    = (const float*)d_in[6];
  const float* b_nb    = (const float*)d_in[7];
  const float* align_w = (const float*)d_in[8];
  const float* align_b = (const float*)d_in[9];
  const float* gamma   = (const float*)d_in[10];
  const float* beta    = (const float*)d_in[11];
  float* outp = (float*)d_out;

  char* wsb = (char*)d_ws;
  unsigned short* aT = (unsigned short*)wsb;          // 8 MB
  float* s2g = (float*)(wsb + 8388608);               // 64 KB
  float* v1c = s2g + BB * LL;                         // 257 floats

  agemm_kernel<<<256, 512, 0, stream>>>(atom, W_nb, b_nb, W_mol, b_mol,
                                        align_w, align_b, aT, s2g, v1c);
  attn_kernel<<<256, 512, 0, stream>>>(aT, mol, v1c, s2g, amask, smask,
                                       gamma, beta, outp);
}